// Round 2
// baseline (177.232 us; speedup 1.0000x reference)
//
#include <hip/hip_runtime.h>
#include <math.h>

// Problem constants (from reference): B=16, K=64, H=160, W=160
#define KK 64
#define HH 160
#define WW 160
#define HWPIX (HH * WW)   // 25600
#define EPSF 1e-5f

// ---------------------------------------------------------------------------
// Kernel 1: inv_denom[b, p] = 1 / (sum_k exp2(arg_k(p)) + EPS/den)
// Pure compute + tiny (1.6 MB) linear write. 2 pixels/thread (W=160 is even,
// so an (even, odd) pixel pair never crosses a row boundary).
// ---------------------------------------------------------------------------
__global__ __launch_bounds__(256) void denom_kernel(
    const float* __restrict__ kp,     // [B, K, 2] (x, y)
    const float* __restrict__ sx_p,
    const float* __restrict__ sy_p,
    const float* __restrict__ rho_p,
    float* __restrict__ invden)       // [B, H*W]
{
    __shared__ float2 skp[KK];

    const int b   = blockIdx.y;
    const int tid = threadIdx.x;
    if (tid < KK) skp[tid] = ((const float2*)(kp + (size_t)b * KK * 2))[tid];

    const float sx  = sx_p[0];
    const float sy  = sy_p[0];
    const float rho = rho_p[0];
    __syncthreads();

    const float L2E  = 1.44269504088896340736f;
    const float omr2 = 1.0f - rho * rho;
    const float num1 = -0.5f / omr2;
    const float ca   = num1 / (sy * sy) * L2E;                 // * dy^2
    const float cb   = num1 / (sx * sx) * L2E;                 // * dx^2
    const float cc   = num1 * (-2.0f * rho / (sx * sy)) * L2E; // * dy*dx
    const float epsod = EPSF * (2.0f * 3.14159265358979323846f * sx * sy * sqrtf(omr2));

    const int p0 = blockIdx.x * 512 + tid * 2;   // grid.x = HWPIX/512 = 50
    const int i  = p0 / WW;
    const int j  = p0 - i * WW;
    const float fi  = (float)i;
    const float fj0 = (float)j;
    const float fj1 = fj0 + 1.0f;

    float sum0 = 0.0f, sum1 = 0.0f;
#pragma unroll
    for (int k = 0; k < KK; ++k) {
        const float dy   = fi - skp[k].y;
        const float ady  = ca * dy * dy;   // ca*dy^2
        const float cdy  = cc * dy;        // cc*dy
        const float dx0  = fj0 - skp[k].x;
        const float dx1  = fj1 - skp[k].x;
        const float a0   = fmaf(cdy, dx0, fmaf(cb * dx0, dx0, ady));
        const float a1   = fmaf(cdy, dx1, fmaf(cb * dx1, dx1, ady));
        sum0 += __builtin_amdgcn_exp2f(a0);
        sum1 += __builtin_amdgcn_exp2f(a1);
    }

    float2 r;
    r.x = 1.0f / (sum0 + epsod);
    r.y = 1.0f / (sum1 + epsod);
    *(float2*)(invden + (size_t)b * HWPIX + p0) = r;
}

// ---------------------------------------------------------------------------
// Kernel 2: out[b,k,p] = exp2(arg_k(p)) * invden[b,p]
// One (b,k) slice per blockIdx.{z,y}: keypoint is wave-uniform (s_load),
// invden reads are L2-resident (1.6 MB reused 64x), stores are perfectly
// linear float4 streams — the fill-kernel access pattern (~6.7 TB/s).
// 4 pixels/thread (W=160 % 4 == 0: a 4-group never crosses a row).
// ---------------------------------------------------------------------------
__global__ __launch_bounds__(256) void score_kernel(
    const float* __restrict__ kp,     // [B, K, 2]
    const float* __restrict__ sx_p,
    const float* __restrict__ sy_p,
    const float* __restrict__ rho_p,
    const float* __restrict__ invden, // [B, H*W]
    float* __restrict__ out)          // [B, K, H, W]
{
    const int b = blockIdx.z;
    const int k = blockIdx.y;

    const float2 kpk = ((const float2*)(kp + (size_t)b * KK * 2))[k]; // uniform
    const float sx  = sx_p[0];
    const float sy  = sy_p[0];
    const float rho = rho_p[0];

    const float L2E  = 1.44269504088896340736f;
    const float omr2 = 1.0f - rho * rho;
    const float num1 = -0.5f / omr2;
    const float ca   = num1 / (sy * sy) * L2E;
    const float cb   = num1 / (sx * sx) * L2E;
    const float cc   = num1 * (-2.0f * rho / (sx * sy)) * L2E;

    const int p0 = blockIdx.x * 1024 + threadIdx.x * 4;  // grid.x = HWPIX/1024 = 25
    const int i  = p0 / WW;
    const int j  = p0 - i * WW;

    const float dy  = (float)i - kpk.y;
    const float ady = ca * dy * dy;
    const float cdy = cc * dy;
    const float dx0 = (float)j - kpk.x;

    const float4 inv = *(const float4*)(invden + (size_t)b * HWPIX + p0);

    float4 o;
    {
        const float a = fmaf(cdy, dx0, fmaf(cb * dx0, dx0, ady));
        o.x = __builtin_amdgcn_exp2f(a) * inv.x;
    }
    {
        const float dx = dx0 + 1.0f;
        const float a = fmaf(cdy, dx, fmaf(cb * dx, dx, ady));
        o.y = __builtin_amdgcn_exp2f(a) * inv.y;
    }
    {
        const float dx = dx0 + 2.0f;
        const float a = fmaf(cdy, dx, fmaf(cb * dx, dx, ady));
        o.z = __builtin_amdgcn_exp2f(a) * inv.z;
    }
    {
        const float dx = dx0 + 3.0f;
        const float a = fmaf(cdy, dx, fmaf(cb * dx, dx, ady));
        o.w = __builtin_amdgcn_exp2f(a) * inv.w;
    }

    *(float4*)(out + ((size_t)(b * KK + k) * HWPIX) + p0) = o;
}

extern "C" void kernel_launch(void* const* d_in, const int* in_sizes, int n_in,
                              void* d_out, int out_size, void* d_ws, size_t ws_size,
                              hipStream_t stream) {
    const float* kp    = (const float*)d_in[0];  // keypoints [B,K,2]
    const float* sx_p  = (const float*)d_in[1];
    const float* sy_p  = (const float*)d_in[2];
    const float* rho_p = (const float*)d_in[3];
    // d_in[4] = DetectionMap: values unused by the reference (shape only)
    float* out    = (float*)d_out;
    float* invden = (float*)d_ws;   // needs B*H*W*4 = 1.6 MB of ws

    const int B = in_sizes[0] / (KK * 2);   // 16

    dim3 grid1(HWPIX / 512, B);             // (50, 16), 256 thr, 2 px/thread
    denom_kernel<<<grid1, 256, 0, stream>>>(kp, sx_p, sy_p, rho_p, invden);

    dim3 grid2(HWPIX / 1024, KK, B);        // (25, 64, 16), 256 thr, 4 px/thread
    score_kernel<<<grid2, 256, 0, stream>>>(kp, sx_p, sy_p, rho_p, invden, out);
}

// Round 4
// 174.251 us; speedup vs baseline: 1.0171x; 1.0171x over previous
//
#include <hip/hip_runtime.h>

// Problem constants (from reference): B=16, K=64, H=160, W=160
#define KK 64
#define HH 160
#define WW 160
#define HWPIX (HH * WW)   // 25600
#define EPSF 1e-5f

// Raw clang vector type — __builtin_nontemporal_store rejects HIP's float4
// class; it requires a vector of scalars.
typedef float vfloat4 __attribute__((ext_vector_type(4)));

// Fused single kernel. Each thread owns 4 consecutive pixels (same row:
// W=160 % 4 == 0). Phase 1: accumulate the 4 softmax-style denominators
// over all 64 keypoints (exps not kept -> no big register array).
// Phase 2: recompute each exp and write out[b,k,p0..p0+3] as nontemporal
// float4 (1 KB per wave store instruction, no L2 pollution).
// den cancels algebraically: out = e_k / (sum_k e + EPS/den).
__global__ __launch_bounds__(256) void recon_confmap_fused(
    const float* __restrict__ kp,     // [B, K, 2] (x, y)
    const float* __restrict__ sx_p,
    const float* __restrict__ sy_p,
    const float* __restrict__ rho_p,
    float* __restrict__ out)          // [B, K, H, W]
{
    __shared__ float2 skp[KK];

    const int b   = blockIdx.y;
    const int tid = threadIdx.x;
    if (tid < KK) skp[tid] = ((const float2*)(kp + (size_t)b * KK * 2))[tid];

    const float sx  = sx_p[0];
    const float sy  = sy_p[0];
    const float rho = rho_p[0];
    __syncthreads();

    const float L2E  = 1.44269504088896340736f;
    const float omr2 = 1.0f - rho * rho;
    const float num1 = -0.5f / omr2;
    const float ca   = num1 / (sy * sy) * L2E;                 // * dy^2
    const float cb   = num1 / (sx * sx) * L2E;                 // * dx^2
    const float cc   = num1 * (-2.0f * rho / (sx * sy)) * L2E; // * dy*dx
    const float epsod = EPSF * (2.0f * 3.14159265358979323846f * sx * sy * sqrtf(omr2));

    const int p0 = blockIdx.x * 1024 + tid * 4;  // grid.x = HWPIX/1024 = 25
    const int i  = p0 / WW;
    const int j  = p0 - i * WW;
    const float fi  = (float)i;
    const float fj  = (float)j;

    // ---- Phase 1: denominators for the 4 pixels ----
    float s0 = 0.0f, s1 = 0.0f, s2 = 0.0f, s3 = 0.0f;
#pragma unroll
    for (int k = 0; k < KK; ++k) {
        const float dy  = fi - skp[k].y;
        const float ady = ca * dy * dy;
        const float cdy = cc * dy;
        const float dx0 = fj - skp[k].x;
        const float dx1 = dx0 + 1.0f;
        const float dx2 = dx0 + 2.0f;
        const float dx3 = dx0 + 3.0f;
        s0 += __builtin_amdgcn_exp2f(fmaf(cdy, dx0, fmaf(cb * dx0, dx0, ady)));
        s1 += __builtin_amdgcn_exp2f(fmaf(cdy, dx1, fmaf(cb * dx1, dx1, ady)));
        s2 += __builtin_amdgcn_exp2f(fmaf(cdy, dx2, fmaf(cb * dx2, dx2, ady)));
        s3 += __builtin_amdgcn_exp2f(fmaf(cdy, dx3, fmaf(cb * dx3, dx3, ady)));
    }

    const float i0 = 1.0f / (s0 + epsod);
    const float i1 = 1.0f / (s1 + epsod);
    const float i2 = 1.0f / (s2 + epsod);
    const float i3 = 1.0f / (s3 + epsod);

    // ---- Phase 2: recompute exps, scale, stream out ----
    float* op = out + (size_t)b * KK * HWPIX + p0;
#pragma unroll
    for (int k = 0; k < KK; ++k) {
        const float dy  = fi - skp[k].y;
        const float ady = ca * dy * dy;
        const float cdy = cc * dy;
        const float dx0 = fj - skp[k].x;
        const float dx1 = dx0 + 1.0f;
        const float dx2 = dx0 + 2.0f;
        const float dx3 = dx0 + 3.0f;
        vfloat4 o;
        o.x = __builtin_amdgcn_exp2f(fmaf(cdy, dx0, fmaf(cb * dx0, dx0, ady))) * i0;
        o.y = __builtin_amdgcn_exp2f(fmaf(cdy, dx1, fmaf(cb * dx1, dx1, ady))) * i1;
        o.z = __builtin_amdgcn_exp2f(fmaf(cdy, dx2, fmaf(cb * dx2, dx2, ady))) * i2;
        o.w = __builtin_amdgcn_exp2f(fmaf(cdy, dx3, fmaf(cb * dx3, dx3, ady))) * i3;
        __builtin_nontemporal_store(o, (vfloat4*)(op + (size_t)k * HWPIX));
    }
}

extern "C" void kernel_launch(void* const* d_in, const int* in_sizes, int n_in,
                              void* d_out, int out_size, void* d_ws, size_t ws_size,
                              hipStream_t stream) {
    const float* kp    = (const float*)d_in[0];  // keypoints [B,K,2]
    const float* sx_p  = (const float*)d_in[1];
    const float* sy_p  = (const float*)d_in[2];
    const float* rho_p = (const float*)d_in[3];
    // d_in[4] = DetectionMap: values unused by the reference (shape only)
    float* out = (float*)d_out;

    const int B = in_sizes[0] / (KK * 2);   // 16
    dim3 grid(HWPIX / 1024, B);             // (25, 16) = 400 blocks, 4 px/thread
    recon_confmap_fused<<<grid, 256, 0, stream>>>(kp, sx_p, sy_p, rho_p, out);
}